// Round 12
// baseline (354.000 us; speedup 1.0000x reference)
//
#include <hip/hip_runtime.h>
#include <math.h>

// Problem constants (match reference setup_inputs)
#define N_NODES   50000
#define E0_EDGES  800000
#define E_TOT     (E0_EDGES + N_NODES)   // self-loops appended
#define FIN       128
#define F1        256                    // HEADS*OUT_CH layer1
#define H1        4
#define C2        64
#define NEG_SLOPE 0.2f

typedef short bf16x8 __attribute__((ext_vector_type(8)));
typedef float f32x4  __attribute__((ext_vector_type(4)));

__device__ __forceinline__ unsigned short f2bf(float f) {
  unsigned u = __float_as_uint(f);
  u = (u + 0x7FFFu + ((u >> 16) & 1u)) >> 16;
  return (unsigned short)u;
}
__device__ __forceinline__ float bf2f(unsigned short h) {
  return __uint_as_float((unsigned)h << 16);
}
__device__ __forceinline__ float leaky(float v) {
  return v >= 0.f ? v : NEG_SLOPE * v;
}

// ---------------------------------------------------------------------------
// CSR-by-dst build. edge_index int32. ei[0..E0)=src, ei[E0..2E0)=dst.
// ---------------------------------------------------------------------------
__global__ __launch_bounds__(256) void deg_kernel(
    const int* __restrict__ ei, int* __restrict__ count) {
  int e = blockIdx.x * 256 + threadIdx.x;
  if (e >= E_TOT) return;
  int dst = (e < E0_EDGES) ? ei[E0_EDGES + e] : (e - E0_EDGES);
  atomicAdd(&count[dst], 1);
}

// Parallel exclusive scan over n=50000 in 3 tiny kernels (chunk = 256).
__global__ __launch_bounds__(256) void scanA_kernel(
    const int* __restrict__ cnt, int* __restrict__ bsum, int n) {
  int i = blockIdx.x * 256 + threadIdx.x;
  int v = (i < n) ? cnt[i] : 0;
#pragma unroll
  for (int d = 1; d < 64; d <<= 1) v += __shfl_xor(v, d);
  __shared__ int ws[4];
  if ((threadIdx.x & 63) == 0) ws[threadIdx.x >> 6] = v;
  __syncthreads();
  if (threadIdx.x == 0) bsum[blockIdx.x] = ws[0] + ws[1] + ws[2] + ws[3];
}

__global__ __launch_bounds__(256) void scanB_kernel(
    const int* __restrict__ bsum, int* __restrict__ bexcl,
    int* __restrict__ off_n, int nb) {
  const int t = threadIdx.x, lane = t & 63, wid = t >> 6;
  int v = (t < nb) ? bsum[t] : 0;
  int sv = v;
#pragma unroll
  for (int d = 1; d < 64; d <<= 1) {
    int u = __shfl_up(sv, d);
    if (lane >= d) sv += u;
  }
  __shared__ int ws[4];
  if (lane == 63) ws[wid] = sv;
  __syncthreads();
  int add = 0;
  for (int k = 0; k < wid; ++k) add += ws[k];
  int incl = sv + add;
  if (t < nb) bexcl[t] = incl - v;
  if (t == 255) off_n[0] = incl;   // grand total -> offset[n]
}

__global__ __launch_bounds__(256) void scanC_kernel(
    const int* __restrict__ cnt, const int* __restrict__ bexcl,
    int* __restrict__ off, int n) {
  const int t = threadIdx.x, lane = t & 63, wid = t >> 6;
  int i = blockIdx.x * 256 + t;
  int v = (i < n) ? cnt[i] : 0;
  int sv = v;
#pragma unroll
  for (int d = 1; d < 64; d <<= 1) {
    int u = __shfl_up(sv, d);
    if (lane >= d) sv += u;
  }
  __shared__ int ws[4];
  if (lane == 63) ws[wid] = sv;
  __syncthreads();
  int add = 0;
  for (int k = 0; k < wid; ++k) add += ws[k];
  if (i < n) off[i] = sv + add - v + bexcl[blockIdx.x];
}

// Plain scatter: only the 4B csr_src write (minimal write amplification).
__global__ __launch_bounds__(256) void scatter_kernel(
    const int* __restrict__ ei, const int* __restrict__ offset,
    int* __restrict__ cursor, int* __restrict__ csr_src) {
  int e = blockIdx.x * 256 + threadIdx.x;
  if (e >= E_TOT) return;
  int src, dst;
  if (e < E0_EDGES) { src = ei[e]; dst = ei[E0_EDGES + e]; }
  else              { src = e - E0_EDGES; dst = src; }
  int pos = offset[dst] + atomicAdd(&cursor[dst], 1);
  csr_src[pos] = src;
}

// ---------------------------------------------------------------------------
// Edge-weight precompute, CSR order (coalesced writes). Layer 1: float4/edge.
// wave per node (4 nodes/block), lanes stride the node's edge range.
// ---------------------------------------------------------------------------
__global__ __launch_bounds__(256) void w1_kernel(
    const float* __restrict__ as1, const float* __restrict__ ad1,
    const int* __restrict__ csr_src, const int* __restrict__ offset,
    float* __restrict__ w4, int n) {
  const int lane = threadIdx.x & 63;
  const int node = blockIdx.x * 4 + (threadIdx.x >> 6);
  if (node >= n) return;
  const int beg = offset[node], end = offset[node + 1];
  const float4 d4 = *reinterpret_cast<const float4*>(&ad1[node * H1]);
  for (int e = beg + lane; e < end; e += 64) {
    const int s = csr_src[e];
    const float4 s4 = *reinterpret_cast<const float4*>(&as1[s * H1]);
    float4 w;
    w.x = __expf(leaky(s4.x + d4.x));
    w.y = __expf(leaky(s4.y + d4.y));
    w.z = __expf(leaky(s4.z + d4.z));
    w.w = __expf(leaky(s4.w + d4.w));
    *reinterpret_cast<float4*>(&w4[(size_t)e * 4]) = w;
  }
}

// Layer 2: scalar weight per edge.
__global__ __launch_bounds__(256) void w2_kernel(
    const float* __restrict__ as2, const float* __restrict__ ad2,
    const int* __restrict__ csr_src, const int* __restrict__ offset,
    float* __restrict__ w2, int n) {
  const int lane = threadIdx.x & 63;
  const int node = blockIdx.x * 4 + (threadIdx.x >> 6);
  if (node >= n) return;
  const int beg = offset[node], end = offset[node + 1];
  const float dv = ad2[node];
  for (int e = beg + lane; e < end; e += 64)
    w2[e] = __expf(leaky(as2[csr_src[e]] + dv));
}

// ---------------------------------------------------------------------------
// Layer-1 GEMM + fused alphas1. h1 = x(fp32) @ W1(fp32), bf16 out + fp32 acc.
// grid = (ceil(M/64), 2); gy=0 -> heads 0,1; gy=1 -> heads 2,3.
// Frag maps (mfma_f32_16x16x32_bf16, HW-verified r7):
//   A: row=lane&15, k=8*(lane>>4)+j   B: col=lane&15, same k
//   D: col=lane&15, row=4*(lane>>4)+reg
// ---------------------------------------------------------------------------
__global__ __launch_bounds__(256) void gemm1_kernel(
    const float* __restrict__ A, const float* __restrict__ B,
    unsigned short* __restrict__ C, float* __restrict__ as1,
    float* __restrict__ ad1, const float* __restrict__ a_s,
    const float* __restrict__ a_d, int M) {
  constexpr int K = FIN, BN = 128, KP = K + 8, NF = BN / 16;
  __shared__ unsigned short BT[BN * KP];   // 34.8 KB
  const int tid = threadIdx.x, lane = tid & 63, wid = tid >> 6;
  const int gy = blockIdx.y, n0 = gy * BN;

  // stage B^T with fp32->bf16 conversion
  for (int idx = tid; idx < K * (BN / 8); idx += 256) {
    int k = idx >> 4;          // BN/8 == 16
    int c = idx & 15;
    const float* src = &B[(size_t)k * F1 + n0 + c * 8];
    float4 lo = *reinterpret_cast<const float4*>(src);
    float4 hi = *reinterpret_cast<const float4*>(src + 4);
    int nb = c * 8;
    BT[(nb + 0) * KP + k] = f2bf(lo.x); BT[(nb + 1) * KP + k] = f2bf(lo.y);
    BT[(nb + 2) * KP + k] = f2bf(lo.z); BT[(nb + 3) * KP + k] = f2bf(lo.w);
    BT[(nb + 4) * KP + k] = f2bf(hi.x); BT[(nb + 5) * KP + k] = f2bf(hi.y);
    BT[(nb + 6) * KP + k] = f2bf(hi.z); BT[(nb + 7) * KP + k] = f2bf(hi.w);
  }
  __syncthreads();

  const int r0 = (blockIdx.x * 4 + wid) * 16;
  if (r0 >= M) return;
  const int nlane = lane & 15;
  const int kg    = (lane >> 4) * 8;
  const int arow  = min(r0 + nlane, M - 1);

  f32x4 acc[NF];
#pragma unroll
  for (int nf = 0; nf < NF; ++nf) acc[nf] = (f32x4){0.f, 0.f, 0.f, 0.f};

  const float* ap = &A[(size_t)arow * K + kg];
#pragma unroll
  for (int kk = 0; kk < K; kk += 32) {
    float4 v0 = *reinterpret_cast<const float4*>(ap + kk);
    float4 v1 = *reinterpret_cast<const float4*>(ap + kk + 4);
    bf16x8 a;
    a[0] = (short)f2bf(v0.x); a[1] = (short)f2bf(v0.y);
    a[2] = (short)f2bf(v0.z); a[3] = (short)f2bf(v0.w);
    a[4] = (short)f2bf(v1.x); a[5] = (short)f2bf(v1.y);
    a[6] = (short)f2bf(v1.z); a[7] = (short)f2bf(v1.w);
#pragma unroll
    for (int nf = 0; nf < NF; ++nf) {
      bf16x8 b = *reinterpret_cast<const bf16x8*>(&BT[(nf * 16 + nlane) * KP + kk + kg]);
      acc[nf] = __builtin_amdgcn_mfma_f32_16x16x32_bf16(a, b, acc[nf], 0, 0, 0);
    }
  }

  // C write (bf16)
  const int crow = r0 + (lane >> 4) * 4;
#pragma unroll
  for (int nf = 0; nf < NF; ++nf) {
    const int cc = n0 + nf * 16 + nlane;
#pragma unroll
    for (int j = 0; j < 4; ++j) {
      int rr = crow + j;
      if (rr < M) C[(size_t)rr * F1 + cc] = f2bf(acc[nf][j]);
    }
  }

  // fused alphas1: per row, dot over this block's 128 cols (2 heads)
#pragma unroll
  for (int j = 0; j < 4; ++j) {
    float ps0 = 0.f, ps1 = 0.f, pd0 = 0.f, pd1 = 0.f;
#pragma unroll
    for (int nf = 0; nf < NF; ++nf) {
      int col = n0 + nf * 16 + nlane;
      float v = acc[nf][j];
      float sc = a_s[col], dc = a_d[col];
      if (nf < 4) { ps0 = fmaf(v, sc, ps0); pd0 = fmaf(v, dc, pd0); }
      else        { ps1 = fmaf(v, sc, ps1); pd1 = fmaf(v, dc, pd1); }
    }
#pragma unroll
    for (int d = 1; d < 16; d <<= 1) {
      ps0 += __shfl_xor(ps0, d); ps1 += __shfl_xor(ps1, d);
      pd0 += __shfl_xor(pd0, d); pd1 += __shfl_xor(pd1, d);
    }
    int row = crow + j;
    if (nlane == 0 && row < M) {
      float2 s2 = {ps0, ps1}, d2 = {pd0, pd1};
      *reinterpret_cast<float2*>(&as1[row * 4 + gy * 2]) = s2;
      *reinterpret_cast<float2*>(&ad1[row * 4 + gy * 2]) = d2;
    }
  }
}

// ---------------------------------------------------------------------------
// Layer-2 GEMM + fused alphas2. h2 = out1(bf16) @ W2(fp32). BN=64 (full width).
// ---------------------------------------------------------------------------
__global__ __launch_bounds__(256) void gemm2_kernel(
    const unsigned short* __restrict__ A, const float* __restrict__ B,
    unsigned short* __restrict__ C, float* __restrict__ as2,
    float* __restrict__ ad2, const float* __restrict__ a_s,
    const float* __restrict__ a_d, int M) {
  constexpr int K = F1, BN = 64, KP = K + 8, NF = BN / 16;
  __shared__ unsigned short BT[BN * KP];   // 33.8 KB
  const int tid = threadIdx.x, lane = tid & 63, wid = tid >> 6;

  for (int idx = tid; idx < K * (BN / 8); idx += 256) {
    int k = idx >> 3;          // BN/8 == 8
    int c = idx & 7;
    const float* src = &B[(size_t)k * C2 + c * 8];
    float4 lo = *reinterpret_cast<const float4*>(src);
    float4 hi = *reinterpret_cast<const float4*>(src + 4);
    int nb = c * 8;
    BT[(nb + 0) * KP + k] = f2bf(lo.x); BT[(nb + 1) * KP + k] = f2bf(lo.y);
    BT[(nb + 2) * KP + k] = f2bf(lo.z); BT[(nb + 3) * KP + k] = f2bf(lo.w);
    BT[(nb + 4) * KP + k] = f2bf(hi.x); BT[(nb + 5) * KP + k] = f2bf(hi.y);
    BT[(nb + 6) * KP + k] = f2bf(hi.z); BT[(nb + 7) * KP + k] = f2bf(hi.w);
  }
  __syncthreads();

  const int r0 = (blockIdx.x * 4 + wid) * 16;
  if (r0 >= M) return;
  const int nlane = lane & 15;
  const int kg    = (lane >> 4) * 8;
  const int arow  = min(r0 + nlane, M - 1);

  f32x4 acc[NF];
#pragma unroll
  for (int nf = 0; nf < NF; ++nf) acc[nf] = (f32x4){0.f, 0.f, 0.f, 0.f};

  const unsigned short* ap = &A[(size_t)arow * K + kg];
#pragma unroll
  for (int kk = 0; kk < K; kk += 32) {
    bf16x8 a = *reinterpret_cast<const bf16x8*>(ap + kk);
#pragma unroll
    for (int nf = 0; nf < NF; ++nf) {
      bf16x8 b = *reinterpret_cast<const bf16x8*>(&BT[(nf * 16 + nlane) * KP + kk + kg]);
      acc[nf] = __builtin_amdgcn_mfma_f32_16x16x32_bf16(a, b, acc[nf], 0, 0, 0);
    }
  }

  const int crow = r0 + (lane >> 4) * 4;
#pragma unroll
  for (int nf = 0; nf < NF; ++nf) {
    const int cc = nf * 16 + nlane;
#pragma unroll
    for (int j = 0; j < 4; ++j) {
      int rr = crow + j;
      if (rr < M) C[(size_t)rr * C2 + cc] = f2bf(acc[nf][j]);
    }
  }

  // fused alphas2 (H=1): dot over all 64 cols
#pragma unroll
  for (int j = 0; j < 4; ++j) {
    float ps = 0.f, pd = 0.f;
#pragma unroll
    for (int nf = 0; nf < NF; ++nf) {
      int col = nf * 16 + nlane;
      float v = acc[nf][j];
      ps = fmaf(v, a_s[col], ps);
      pd = fmaf(v, a_d[col], pd);
    }
#pragma unroll
    for (int d = 1; d < 16; d <<= 1) {
      ps += __shfl_xor(ps, d);
      pd += __shfl_xor(pd, d);
    }
    int row = crow + j;
    if (nlane == 0 && row < M) { as2[row] = ps; ad2[row] = pd; }
  }
}

// ---------------------------------------------------------------------------
// Aggregation layer 1: wave per dst node (4/block), single pass, weights
// precomputed in w4 (CSR order -> coalesced reads). Inner loop is pure
// gather+FMA; only dependent chain is csr_src -> h-row.
// Node range [node0, n). Epilogue: /den, +b1, ReLU -> bf16.
// ---------------------------------------------------------------------------
__global__ __launch_bounds__(256) void aggregate1_kernel(
    const unsigned short* __restrict__ h1b, const float* __restrict__ w4,
    const int* __restrict__ csr_src, const int* __restrict__ offset,
    const float* __restrict__ b1, unsigned short* __restrict__ out1b,
    int node0, int n) {
  const int lane = threadIdx.x & 63;
  const int node = node0 + blockIdx.x * 4 + (threadIdx.x >> 6);
  if (node >= n) return;
  const int beg = offset[node], end = offset[node + 1];
  const int hl = lane >> 4;
  const unsigned loff = (unsigned)(lane * 4);

  float4 acc = make_float4(0.f, 0.f, 0.f, 0.f);
  float den = 0.f;
  int e = beg;
  for (; e + 7 < end; e += 8) {
    int s[8];
    float wv[8];
    ushort4 r[8];
#pragma unroll
    for (int i = 0; i < 8; ++i) s[i] = csr_src[e + i];
#pragma unroll
    for (int i = 0; i < 8; ++i) wv[i] = w4[(size_t)(e + i) * 4 + hl];
#pragma unroll
    for (int i = 0; i < 8; ++i)
      r[i] = *reinterpret_cast<const ushort4*>(h1b + (unsigned)(s[i] * F1) + loff);
#pragma unroll
    for (int i = 0; i < 8; ++i) {
      den += wv[i];
      acc.x = fmaf(wv[i], bf2f(r[i].x), acc.x);
      acc.y = fmaf(wv[i], bf2f(r[i].y), acc.y);
      acc.z = fmaf(wv[i], bf2f(r[i].z), acc.z);
      acc.w = fmaf(wv[i], bf2f(r[i].w), acc.w);
    }
  }
  for (; e < end; ++e) {
    const int s0 = csr_src[e];
    const float w = w4[(size_t)e * 4 + hl];
    den += w;
    const ushort4 r0 = *reinterpret_cast<const ushort4*>(h1b + (unsigned)(s0 * F1) + loff);
    acc.x = fmaf(w, bf2f(r0.x), acc.x);
    acc.y = fmaf(w, bf2f(r0.y), acc.y);
    acc.z = fmaf(w, bf2f(r0.z), acc.z);
    acc.w = fmaf(w, bf2f(r0.w), acc.w);
  }
  const float inv = 1.f / (den + 1e-16f);
  const float4 bb = *reinterpret_cast<const float4*>(&b1[lane * 4]);
  ushort4 ob;
  ob.x = f2bf(fmaxf(fmaf(acc.x, inv, bb.x), 0.f));
  ob.y = f2bf(fmaxf(fmaf(acc.y, inv, bb.y), 0.f));
  ob.z = f2bf(fmaxf(fmaf(acc.z, inv, bb.z), 0.f));
  ob.w = f2bf(fmaxf(fmaf(acc.w, inv, bb.w), 0.f));
  *reinterpret_cast<ushort4*>(&out1b[(size_t)node * F1 + lane * 4]) = ob;
}

// ---------------------------------------------------------------------------
// Aggregation layer 2: wave per dst node, lane owns channel `lane`.
// Weights precomputed in w2 (coalesced). Output fp32 (+b2, no ReLU).
// ---------------------------------------------------------------------------
__global__ __launch_bounds__(256) void aggregate2_kernel(
    const unsigned short* __restrict__ h2b, const float* __restrict__ w2,
    const int* __restrict__ csr_src, const int* __restrict__ offset,
    const float* __restrict__ b2, float* __restrict__ out, int n) {
  const int lane = threadIdx.x & 63;
  const int node = blockIdx.x * 4 + (threadIdx.x >> 6);
  if (node >= n) return;
  const int beg = offset[node], end = offset[node + 1];

  float acc = 0.f;
  float den = 0.f;
  int e = beg;
  for (; e + 7 < end; e += 8) {
    int s[8];
    float wv[8];
    unsigned short r[8];
#pragma unroll
    for (int i = 0; i < 8; ++i) s[i] = csr_src[e + i];
#pragma unroll
    for (int i = 0; i < 8; ++i) wv[i] = w2[e + i];
#pragma unroll
    for (int i = 0; i < 8; ++i) r[i] = h2b[(unsigned)(s[i] * C2) + lane];
#pragma unroll
    for (int i = 0; i < 8; ++i) {
      den += wv[i];
      acc = fmaf(wv[i], bf2f(r[i]), acc);
    }
  }
  for (; e < end; ++e) {
    const int s0 = csr_src[e];
    const float w = w2[e];
    den += w;
    acc = fmaf(w, bf2f(h2b[(unsigned)(s0 * C2) + lane]), acc);
  }
  out[(size_t)node * C2 + lane] = fmaf(acc, 1.f / (den + 1e-16f), b2[lane]);
}

// ---------------------------------------------------------------------------
extern "C" void kernel_launch(void* const* d_in, const int* in_sizes, int n_in,
                              void* d_out, int out_size, void* d_ws, size_t ws_size,
                              hipStream_t stream) {
  const float* x      = (const float*)d_in[0];
  const int*   ei     = (const int*)d_in[1];      // int32 (JAX x64 disabled)
  const float* W1     = (const float*)d_in[2];
  const float* a_src1 = (const float*)d_in[3];
  const float* a_dst1 = (const float*)d_in[4];
  const float* b1     = (const float*)d_in[5];
  const float* W2     = (const float*)d_in[6];
  const float* a_src2 = (const float*)d_in[7];
  const float* a_dst2 = (const float*)d_in[8];
  const float* b2     = (const float*)d_in[9];
  float*       out    = (float*)d_out;

  const int n = N_NODES;
  const int nchunks = (n + 255) / 256;   // 196

  // Workspace carve (~80 MiB). h2b aliases h1b; w2 aliases w4 (both dead
  // before their layer-2 reuse).
  char* w = (char*)d_ws;
  unsigned short* h1b   = (unsigned short*)w; w += (size_t)n * F1 * 2;     // 25.6 MB
  unsigned short* out1b = (unsigned short*)w; w += (size_t)n * F1 * 2;     // 25.6 MB
  float*          w4    = (float*)w;          w += (size_t)E_TOT * 4 * 4;  // 13.6 MB
  float*          as1   = (float*)w;          w += (size_t)n * H1 * 4;
  float*          ad1   = (float*)w;          w += (size_t)n * H1 * 4;
  float*          as2   = (float*)w;          w += 200192;
  float*          ad2   = (float*)w;          w += 200192;
  int*            cnt   = (int*)w;            w += 200192;
  int*            cur   = (int*)w;            w += 200192;
  int*            off   = (int*)w;            w += 200704;  // n+1 ints
  int*            bsum  = (int*)w;            w += 1024;
  int*            bexcl = (int*)w;            w += 1024;
  int*            csr   = (int*)w;            w += 3400192;
  unsigned short* h2b   = h1b;                // alias
  float*          w2    = w4;                 // alias (w4 dead after agg1)

  // --- CSR degree+scan+scatter ---
  hipMemsetAsync(cnt, 0, 2 * 200192, stream);   // zeroes cnt AND cur
  deg_kernel<<<(E_TOT + 255) / 256, 256, 0, stream>>>(ei, cnt);
  scanA_kernel<<<nchunks, 256, 0, stream>>>(cnt, bsum, n);
  scanB_kernel<<<1, 256, 0, stream>>>(bsum, bexcl, &off[n], nchunks);
  scanC_kernel<<<nchunks, 256, 0, stream>>>(cnt, bexcl, off, n);
  scatter_kernel<<<(E_TOT + 255) / 256, 256, 0, stream>>>(ei, off, cur, csr);

  // --- Layer 1: GEMM (h1b + as1/ad1), edge weights, aggregation ---
  {
    dim3 grid((n + 63) / 64, 2);
    gemm1_kernel<<<grid, 256, 0, stream>>>(x, W1, h1b, as1, ad1, a_src1, a_dst1, n);
  }
  w1_kernel<<<(n + 3) / 4, 256, 0, stream>>>(as1, ad1, csr, off, w4, n);
  {
    const int half = 25000;
    aggregate1_kernel<<<(half + 3) / 4, 256, 0, stream>>>(
        h1b, w4, csr, off, b1, out1b, 0, half);
    aggregate1_kernel<<<(n - half + 3) / 4, 256, 0, stream>>>(
        h1b, w4, csr, off, b1, out1b, half, n);
  }

  // --- Layer 2: GEMM (h2b + as2/ad2), edge weights, aggregation ---
  {
    dim3 grid((n + 63) / 64, 1);
    gemm2_kernel<<<grid, 256, 0, stream>>>(out1b, W2, h2b, as2, ad2, a_src2, a_dst2, n);
  }
  w2_kernel<<<(n + 3) / 4, 256, 0, stream>>>(as2, ad2, csr, off, w2, n);
  aggregate2_kernel<<<(n + 3) / 4, 256, 0, stream>>>(h2b, w2, csr, off, b2, out, n);
}

// Round 13
// 297.233 us; speedup vs baseline: 1.1910x; 1.1910x over previous
//
#include <hip/hip_runtime.h>
#include <math.h>

// Problem constants (match reference setup_inputs)
#define N_NODES   50000
#define E0_EDGES  800000
#define E_TOT     (E0_EDGES + N_NODES)   // self-loops appended
#define FIN       128
#define F1        256                    // HEADS*OUT_CH layer1
#define H1        4
#define C2        64
#define NEG_SLOPE 0.2f

#define NBX1      ((N_NODES + 63) / 64)        // 782 gemm1 row-blocks
#define GEMM1_BLOCKS (NBX1 * 2)                // x2 col-halves
#define SCAT_BLOCKS  ((E_TOT + 255) / 256)     // 3321

typedef short bf16x8 __attribute__((ext_vector_type(8)));
typedef float f32x4  __attribute__((ext_vector_type(4)));

__device__ __forceinline__ unsigned short f2bf(float f) {
  unsigned u = __float_as_uint(f);
  u = (u + 0x7FFFu + ((u >> 16) & 1u)) >> 16;
  return (unsigned short)u;
}
__device__ __forceinline__ float bf2f(unsigned short h) {
  return __uint_as_float((unsigned)h << 16);
}
__device__ __forceinline__ float leaky(float v) {
  return v >= 0.f ? v : NEG_SLOPE * v;
}

// ---------------------------------------------------------------------------
// deg + rank capture: rank[e] = this edge's arrival index among its dst's
// edges (atomicAdd return). Removes ALL atomics from the later scatter.
// ---------------------------------------------------------------------------
__global__ __launch_bounds__(256) void deg_kernel(
    const int* __restrict__ ei, int* __restrict__ count,
    int* __restrict__ rank) {
  int e = blockIdx.x * 256 + threadIdx.x;
  if (e >= E_TOT) return;
  int dst = (e < E0_EDGES) ? ei[E0_EDGES + e] : (e - E0_EDGES);
  rank[e] = atomicAdd(&count[dst], 1);
}

// Parallel exclusive scan over n=50000 in 3 tiny kernels (chunk = 256).
__global__ __launch_bounds__(256) void scanA_kernel(
    const int* __restrict__ cnt, int* __restrict__ bsum, int n) {
  int i = blockIdx.x * 256 + threadIdx.x;
  int v = (i < n) ? cnt[i] : 0;
#pragma unroll
  for (int d = 1; d < 64; d <<= 1) v += __shfl_xor(v, d);
  __shared__ int ws[4];
  if ((threadIdx.x & 63) == 0) ws[threadIdx.x >> 6] = v;
  __syncthreads();
  if (threadIdx.x == 0) bsum[blockIdx.x] = ws[0] + ws[1] + ws[2] + ws[3];
}

__global__ __launch_bounds__(256) void scanB_kernel(
    const int* __restrict__ bsum, int* __restrict__ bexcl,
    int* __restrict__ off_n, int nb) {
  const int t = threadIdx.x, lane = t & 63, wid = t >> 6;
  int v = (t < nb) ? bsum[t] : 0;
  int sv = v;
#pragma unroll
  for (int d = 1; d < 64; d <<= 1) {
    int u = __shfl_up(sv, d);
    if (lane >= d) sv += u;
  }
  __shared__ int ws[4];
  if (lane == 63) ws[wid] = sv;
  __syncthreads();
  int add = 0;
  for (int k = 0; k < wid; ++k) add += ws[k];
  int incl = sv + add;
  if (t < nb) bexcl[t] = incl - v;
  if (t == 255) off_n[0] = incl;   // grand total -> offset[n]
}

__global__ __launch_bounds__(256) void scanC_kernel(
    const int* __restrict__ cnt, const int* __restrict__ bexcl,
    int* __restrict__ off, int n) {
  const int t = threadIdx.x, lane = t & 63, wid = t >> 6;
  int i = blockIdx.x * 256 + t;
  int v = (i < n) ? cnt[i] : 0;
  int sv = v;
#pragma unroll
  for (int d = 1; d < 64; d <<= 1) {
    int u = __shfl_up(sv, d);
    if (lane >= d) sv += u;
  }
  __shared__ int ws[4];
  if (lane == 63) ws[wid] = sv;
  __syncthreads();
  int add = 0;
  for (int k = 0; k < wid; ++k) add += ws[k];
  if (i < n) off[i] = sv + add - v + bexcl[blockIdx.x];
}

// ---------------------------------------------------------------------------
// FUSED: gemm1 (+alphas1) on blocks [0, GEMM1_BLOCKS) and atomic-free scatter
// on blocks [GEMM1_BLOCKS, +SCAT_BLOCKS). Independent work, overlapped in one
// dispatch instead of serialized on the stream.
// gemm1: h1 = x(fp32) @ W1(fp32) -> bf16; fp32 acc; fused per-row alphas.
// Frag maps (mfma_f32_16x16x32_bf16, HW-verified r7):
//   A: row=lane&15, k=8*(lane>>4)+j   B: col=lane&15, same k
//   D: col=lane&15, row=4*(lane>>4)+reg
// ---------------------------------------------------------------------------
__global__ __launch_bounds__(256) void gemm1_scatter_kernel(
    const float* __restrict__ A, const float* __restrict__ B,
    unsigned short* __restrict__ C, float* __restrict__ as1,
    float* __restrict__ ad1, const float* __restrict__ a_s,
    const float* __restrict__ a_d, int M,
    const int* __restrict__ ei, const int* __restrict__ offset,
    const int* __restrict__ rank, int* __restrict__ csr_src) {
  constexpr int K = FIN, BN = 128, KP = K + 8, NF = BN / 16;
  __shared__ unsigned short BT[BN * KP];   // 34.8 KB (unused by scatter blocks)
  const int bid = blockIdx.x;

  if (bid >= GEMM1_BLOCKS) {
    // ---- scatter part: no atomics (rank precomputed in deg) ----
    int e = (bid - GEMM1_BLOCKS) * 256 + threadIdx.x;
    if (e >= E_TOT) return;
    int src, dst;
    if (e < E0_EDGES) { src = ei[e]; dst = ei[E0_EDGES + e]; }
    else              { src = e - E0_EDGES; dst = src; }
    csr_src[offset[dst] + rank[e]] = src;
    return;
  }

  // ---- gemm1 part ----
  const int bx = bid % NBX1;
  const int gy = bid / NBX1;
  const int tid = threadIdx.x, lane = tid & 63, wid = tid >> 6;
  const int n0 = gy * BN;

  for (int idx = tid; idx < K * (BN / 8); idx += 256) {
    int k = idx >> 4;          // BN/8 == 16
    int c = idx & 15;
    const float* src = &B[(size_t)k * F1 + n0 + c * 8];
    float4 lo = *reinterpret_cast<const float4*>(src);
    float4 hi = *reinterpret_cast<const float4*>(src + 4);
    int nb = c * 8;
    BT[(nb + 0) * KP + k] = f2bf(lo.x); BT[(nb + 1) * KP + k] = f2bf(lo.y);
    BT[(nb + 2) * KP + k] = f2bf(lo.z); BT[(nb + 3) * KP + k] = f2bf(lo.w);
    BT[(nb + 4) * KP + k] = f2bf(hi.x); BT[(nb + 5) * KP + k] = f2bf(hi.y);
    BT[(nb + 6) * KP + k] = f2bf(hi.z); BT[(nb + 7) * KP + k] = f2bf(hi.w);
  }
  __syncthreads();

  const int r0 = (bx * 4 + wid) * 16;
  if (r0 >= M) return;
  const int nlane = lane & 15;
  const int kg    = (lane >> 4) * 8;
  const int arow  = min(r0 + nlane, M - 1);

  f32x4 acc[NF];
#pragma unroll
  for (int nf = 0; nf < NF; ++nf) acc[nf] = (f32x4){0.f, 0.f, 0.f, 0.f};

  const float* ap = &A[(size_t)arow * K + kg];
#pragma unroll
  for (int kk = 0; kk < K; kk += 32) {
    float4 v0 = *reinterpret_cast<const float4*>(ap + kk);
    float4 v1 = *reinterpret_cast<const float4*>(ap + kk + 4);
    bf16x8 a;
    a[0] = (short)f2bf(v0.x); a[1] = (short)f2bf(v0.y);
    a[2] = (short)f2bf(v0.z); a[3] = (short)f2bf(v0.w);
    a[4] = (short)f2bf(v1.x); a[5] = (short)f2bf(v1.y);
    a[6] = (short)f2bf(v1.z); a[7] = (short)f2bf(v1.w);
#pragma unroll
    for (int nf = 0; nf < NF; ++nf) {
      bf16x8 b = *reinterpret_cast<const bf16x8*>(&BT[(nf * 16 + nlane) * KP + kk + kg]);
      acc[nf] = __builtin_amdgcn_mfma_f32_16x16x32_bf16(a, b, acc[nf], 0, 0, 0);
    }
  }

  const int crow = r0 + (lane >> 4) * 4;
#pragma unroll
  for (int nf = 0; nf < NF; ++nf) {
    const int cc = n0 + nf * 16 + nlane;
#pragma unroll
    for (int j = 0; j < 4; ++j) {
      int rr = crow + j;
      if (rr < M) C[(size_t)rr * F1 + cc] = f2bf(acc[nf][j]);
    }
  }

  // fused alphas1: per row, dot over this block's 128 cols (2 heads)
#pragma unroll
  for (int j = 0; j < 4; ++j) {
    float ps0 = 0.f, ps1 = 0.f, pd0 = 0.f, pd1 = 0.f;
#pragma unroll
    for (int nf = 0; nf < NF; ++nf) {
      int col = n0 + nf * 16 + nlane;
      float v = acc[nf][j];
      float sc = a_s[col], dc = a_d[col];
      if (nf < 4) { ps0 = fmaf(v, sc, ps0); pd0 = fmaf(v, dc, pd0); }
      else        { ps1 = fmaf(v, sc, ps1); pd1 = fmaf(v, dc, pd1); }
    }
#pragma unroll
    for (int d = 1; d < 16; d <<= 1) {
      ps0 += __shfl_xor(ps0, d); ps1 += __shfl_xor(ps1, d);
      pd0 += __shfl_xor(pd0, d); pd1 += __shfl_xor(pd1, d);
    }
    int row = crow + j;
    if (nlane == 0 && row < M) {
      float2 s2 = {ps0, ps1}, d2 = {pd0, pd1};
      *reinterpret_cast<float2*>(&as1[row * 4 + gy * 2]) = s2;
      *reinterpret_cast<float2*>(&ad1[row * 4 + gy * 2]) = d2;
    }
  }
}

// ---------------------------------------------------------------------------
// Edge-weight precompute for layer 1, CSR order (coalesced float4 writes).
// ---------------------------------------------------------------------------
__global__ __launch_bounds__(256) void w1_kernel(
    const float* __restrict__ as1, const float* __restrict__ ad1,
    const int* __restrict__ csr_src, const int* __restrict__ offset,
    float* __restrict__ w4, int n) {
  const int lane = threadIdx.x & 63;
  const int node = blockIdx.x * 4 + (threadIdx.x >> 6);
  if (node >= n) return;
  const int beg = offset[node], end = offset[node + 1];
  const float4 d4 = *reinterpret_cast<const float4*>(&ad1[node * H1]);
  for (int e = beg + lane; e < end; e += 64) {
    const int s = csr_src[e];
    const float4 s4 = *reinterpret_cast<const float4*>(&as1[s * H1]);
    float4 w;
    w.x = __expf(leaky(s4.x + d4.x));
    w.y = __expf(leaky(s4.y + d4.y));
    w.z = __expf(leaky(s4.z + d4.z));
    w.w = __expf(leaky(s4.w + d4.w));
    *reinterpret_cast<float4*>(&w4[(size_t)e * 4]) = w;
  }
}

// ---------------------------------------------------------------------------
// Layer-2 GEMM + fused alphas2. h2 = out1(bf16) @ W2(fp32). BN=64.
// ---------------------------------------------------------------------------
__global__ __launch_bounds__(256) void gemm2_kernel(
    const unsigned short* __restrict__ A, const float* __restrict__ B,
    unsigned short* __restrict__ C, float* __restrict__ as2,
    float* __restrict__ ad2, const float* __restrict__ a_s,
    const float* __restrict__ a_d, int M) {
  constexpr int K = F1, BN = 64, KP = K + 8, NF = BN / 16;
  __shared__ unsigned short BT[BN * KP];   // 33.8 KB
  const int tid = threadIdx.x, lane = tid & 63, wid = tid >> 6;

  for (int idx = tid; idx < K * (BN / 8); idx += 256) {
    int k = idx >> 3;          // BN/8 == 8
    int c = idx & 7;
    const float* src = &B[(size_t)k * C2 + c * 8];
    float4 lo = *reinterpret_cast<const float4*>(src);
    float4 hi = *reinterpret_cast<const float4*>(src + 4);
    int nb = c * 8;
    BT[(nb + 0) * KP + k] = f2bf(lo.x); BT[(nb + 1) * KP + k] = f2bf(lo.y);
    BT[(nb + 2) * KP + k] = f2bf(lo.z); BT[(nb + 3) * KP + k] = f2bf(lo.w);
    BT[(nb + 4) * KP + k] = f2bf(hi.x); BT[(nb + 5) * KP + k] = f2bf(hi.y);
    BT[(nb + 6) * KP + k] = f2bf(hi.z); BT[(nb + 7) * KP + k] = f2bf(hi.w);
  }
  __syncthreads();

  const int r0 = (blockIdx.x * 4 + wid) * 16;
  if (r0 >= M) return;
  const int nlane = lane & 15;
  const int kg    = (lane >> 4) * 8;
  const int arow  = min(r0 + nlane, M - 1);

  f32x4 acc[NF];
#pragma unroll
  for (int nf = 0; nf < NF; ++nf) acc[nf] = (f32x4){0.f, 0.f, 0.f, 0.f};

  const unsigned short* ap = &A[(size_t)arow * K + kg];
#pragma unroll
  for (int kk = 0; kk < K; kk += 32) {
    bf16x8 a = *reinterpret_cast<const bf16x8*>(ap + kk);
#pragma unroll
    for (int nf = 0; nf < NF; ++nf) {
      bf16x8 b = *reinterpret_cast<const bf16x8*>(&BT[(nf * 16 + nlane) * KP + kk + kg]);
      acc[nf] = __builtin_amdgcn_mfma_f32_16x16x32_bf16(a, b, acc[nf], 0, 0, 0);
    }
  }

  const int crow = r0 + (lane >> 4) * 4;
#pragma unroll
  for (int nf = 0; nf < NF; ++nf) {
    const int cc = nf * 16 + nlane;
#pragma unroll
    for (int j = 0; j < 4; ++j) {
      int rr = crow + j;
      if (rr < M) C[(size_t)rr * C2 + cc] = f2bf(acc[nf][j]);
    }
  }

  // fused alphas2 (H=1): dot over all 64 cols
#pragma unroll
  for (int j = 0; j < 4; ++j) {
    float ps = 0.f, pd = 0.f;
#pragma unroll
    for (int nf = 0; nf < NF; ++nf) {
      int col = nf * 16 + nlane;
      float v = acc[nf][j];
      ps = fmaf(v, a_s[col], ps);
      pd = fmaf(v, a_d[col], pd);
    }
#pragma unroll
    for (int d = 1; d < 16; d <<= 1) {
      ps += __shfl_xor(ps, d);
      pd += __shfl_xor(pd, d);
    }
    int row = crow + j;
    if (nlane == 0 && row < M) { as2[row] = ps; ad2[row] = pd; }
  }
}

// ---------------------------------------------------------------------------
// Aggregation layer 1: wave per dst node (4/block), single pass, weights
// precomputed in w4 (CSR order). Epilogue: /den, +b1, ReLU -> bf16.
// ---------------------------------------------------------------------------
__global__ __launch_bounds__(256) void aggregate1_kernel(
    const unsigned short* __restrict__ h1b, const float* __restrict__ w4,
    const int* __restrict__ csr_src, const int* __restrict__ offset,
    const float* __restrict__ b1, unsigned short* __restrict__ out1b, int n) {
  const int lane = threadIdx.x & 63;
  const int node = blockIdx.x * 4 + (threadIdx.x >> 6);
  if (node >= n) return;
  const int beg = offset[node], end = offset[node + 1];
  const int hl = lane >> 4;
  const unsigned loff = (unsigned)(lane * 4);

  float4 acc = make_float4(0.f, 0.f, 0.f, 0.f);
  float den = 0.f;
  int e = beg;
  for (; e + 7 < end; e += 8) {
    int s[8];
    float wv[8];
    ushort4 r[8];
#pragma unroll
    for (int i = 0; i < 8; ++i) s[i] = csr_src[e + i];
#pragma unroll
    for (int i = 0; i < 8; ++i) wv[i] = w4[(size_t)(e + i) * 4 + hl];
#pragma unroll
    for (int i = 0; i < 8; ++i)
      r[i] = *reinterpret_cast<const ushort4*>(h1b + (unsigned)(s[i] * F1) + loff);
#pragma unroll
    for (int i = 0; i < 8; ++i) {
      den += wv[i];
      acc.x = fmaf(wv[i], bf2f(r[i].x), acc.x);
      acc.y = fmaf(wv[i], bf2f(r[i].y), acc.y);
      acc.z = fmaf(wv[i], bf2f(r[i].z), acc.z);
      acc.w = fmaf(wv[i], bf2f(r[i].w), acc.w);
    }
  }
  for (; e < end; ++e) {
    const int s0 = csr_src[e];
    const float w = w4[(size_t)e * 4 + hl];
    den += w;
    const ushort4 r0 = *reinterpret_cast<const ushort4*>(h1b + (unsigned)(s0 * F1) + loff);
    acc.x = fmaf(w, bf2f(r0.x), acc.x);
    acc.y = fmaf(w, bf2f(r0.y), acc.y);
    acc.z = fmaf(w, bf2f(r0.z), acc.z);
    acc.w = fmaf(w, bf2f(r0.w), acc.w);
  }
  const float inv = 1.f / (den + 1e-16f);
  const float4 bb = *reinterpret_cast<const float4*>(&b1[lane * 4]);
  ushort4 ob;
  ob.x = f2bf(fmaxf(fmaf(acc.x, inv, bb.x), 0.f));
  ob.y = f2bf(fmaxf(fmaf(acc.y, inv, bb.y), 0.f));
  ob.z = f2bf(fmaxf(fmaf(acc.z, inv, bb.z), 0.f));
  ob.w = f2bf(fmaxf(fmaf(acc.w, inv, bb.w), 0.f));
  *reinterpret_cast<ushort4*>(&out1b[(size_t)node * F1 + lane * 4]) = ob;
}

// ---------------------------------------------------------------------------
// Aggregation layer 2: wave per dst node, lane owns channel `lane`.
// Single pass, inline exp (as2/ad2 are L2-hot 200KB). Output fp32 (+b2).
// ---------------------------------------------------------------------------
__global__ __launch_bounds__(256) void aggregate2_kernel(
    const unsigned short* __restrict__ h2b, const float* __restrict__ as,
    const float* __restrict__ ad, const int* __restrict__ csr_src,
    const int* __restrict__ offset, const float* __restrict__ b2,
    float* __restrict__ out, int n) {
  const int lane = threadIdx.x & 63;
  const int node = blockIdx.x * 4 + (threadIdx.x >> 6);
  if (node >= n) return;
  const int beg = offset[node], end = offset[node + 1];
  const float adv = ad[node];

  float acc = 0.f;
  float den = 0.f;
  int e = beg;
  for (; e + 7 < end; e += 8) {
    int s[8];
    unsigned short r[8];
    float a[8];
#pragma unroll
    for (int i = 0; i < 8; ++i) s[i] = csr_src[e + i];
#pragma unroll
    for (int i = 0; i < 8; ++i) r[i] = h2b[(unsigned)(s[i] * C2) + lane];
#pragma unroll
    for (int i = 0; i < 8; ++i) a[i] = as[s[i]];
#pragma unroll
    for (int i = 0; i < 8; ++i) {
      const float w = __expf(leaky(a[i] + adv));
      den += w;
      acc = fmaf(w, bf2f(r[i]), acc);
    }
  }
  for (; e < end; ++e) {
    const int s0 = csr_src[e];
    const float w = __expf(leaky(as[s0] + adv));
    den += w;
    acc = fmaf(w, bf2f(h2b[(unsigned)(s0 * C2) + lane]), acc);
  }
  out[(size_t)node * C2 + lane] = fmaf(acc, 1.f / (den + 1e-16f), b2[lane]);
}

// ---------------------------------------------------------------------------
extern "C" void kernel_launch(void* const* d_in, const int* in_sizes, int n_in,
                              void* d_out, int out_size, void* d_ws, size_t ws_size,
                              hipStream_t stream) {
  const float* x      = (const float*)d_in[0];
  const int*   ei     = (const int*)d_in[1];      // int32 (JAX x64 disabled)
  const float* W1     = (const float*)d_in[2];
  const float* a_src1 = (const float*)d_in[3];
  const float* a_dst1 = (const float*)d_in[4];
  const float* b1     = (const float*)d_in[5];
  const float* W2     = (const float*)d_in[6];
  const float* a_src2 = (const float*)d_in[7];
  const float* a_dst2 = (const float*)d_in[8];
  const float* b2     = (const float*)d_in[9];
  float*       out    = (float*)d_out;

  const int n = N_NODES;
  const int nchunks = (n + 255) / 256;   // 196

  // Workspace carve (~84 MiB). h2b aliases h1b; w2 unused (agg2 inlines exp).
  char* w = (char*)d_ws;
  unsigned short* h1b   = (unsigned short*)w; w += (size_t)n * F1 * 2;     // 25.6 MB
  unsigned short* out1b = (unsigned short*)w; w += (size_t)n * F1 * 2;     // 25.6 MB
  float*          w4    = (float*)w;          w += (size_t)E_TOT * 4 * 4;  // 13.6 MB
  float*          as1   = (float*)w;          w += (size_t)n * H1 * 4;
  float*          ad1   = (float*)w;          w += (size_t)n * H1 * 4;
  float*          as2   = (float*)w;          w += 200192;
  float*          ad2   = (float*)w;          w += 200192;
  int*            cnt   = (int*)w;            w += 200192;
  int*            off   = (int*)w;            w += 200704;  // n+1 ints
  int*            bsum  = (int*)w;            w += 1024;
  int*            bexcl = (int*)w;            w += 1024;
  int*            rank  = (int*)w;            w += 3400192;
  int*            csr   = (int*)w;            w += 3400192;
  unsigned short* h2b   = h1b;                // alias

  // --- CSR: deg (captures ranks) + parallel scan ---
  hipMemsetAsync(cnt, 0, 200192, stream);
  deg_kernel<<<SCAT_BLOCKS, 256, 0, stream>>>(ei, cnt, rank);
  scanA_kernel<<<nchunks, 256, 0, stream>>>(cnt, bsum, n);
  scanB_kernel<<<1, 256, 0, stream>>>(bsum, bexcl, &off[n], nchunks);
  scanC_kernel<<<nchunks, 256, 0, stream>>>(cnt, bexcl, off, n);

  // --- Fused: gemm1 (+alphas1) overlapped with atomic-free scatter ---
  gemm1_scatter_kernel<<<GEMM1_BLOCKS + SCAT_BLOCKS, 256, 0, stream>>>(
      x, W1, h1b, as1, ad1, a_src1, a_dst1, n, ei, off, rank, csr);

  // --- Layer 1: edge weights + aggregation ---
  w1_kernel<<<(n + 3) / 4, 256, 0, stream>>>(as1, ad1, csr, off, w4, n);
  aggregate1_kernel<<<(n + 3) / 4, 256, 0, stream>>>(h1b, w4, csr, off, b1, out1b, n);

  // --- Layer 2: GEMM (+alphas2) then aggregation (inline weights) ---
  gemm2_kernel<<<(n + 63) / 64, 256, 0, stream>>>(out1b, W2, h2b, as2, ad2,
                                                  a_src2, a_dst2, n);
  aggregate2_kernel<<<(n + 3) / 4, 256, 0, stream>>>(h2b, as2, ad2, csr, off, b2, out, n);
}

// Round 14
// 292.824 us; speedup vs baseline: 1.2089x; 1.0151x over previous
//
#include <hip/hip_runtime.h>
#include <math.h>

// Problem constants (match reference setup_inputs)
#define N_NODES   50000
#define E0_EDGES  800000
#define E_TOT     (E0_EDGES + N_NODES)   // self-loops appended
#define FIN       128
#define F1        256                    // HEADS*OUT_CH layer1
#define H1        4
#define C2        64
#define NEG_SLOPE 0.2f

#define NBX1      ((N_NODES + 63) / 64)        // 782 gemm1 row-blocks
#define GEMM1_BLOCKS (NBX1 * 2)                // x2 col-halves
#define SCAT_BLOCKS  ((E_TOT + 255) / 256)     // 3321

typedef short bf16x8 __attribute__((ext_vector_type(8)));
typedef float f32x4  __attribute__((ext_vector_type(4)));

__device__ __forceinline__ unsigned short f2bf(float f) {
  unsigned u = __float_as_uint(f);
  u = (u + 0x7FFFu + ((u >> 16) & 1u)) >> 16;
  return (unsigned short)u;
}
__device__ __forceinline__ float bf2f(unsigned short h) {
  return __uint_as_float((unsigned)h << 16);
}
__device__ __forceinline__ float leaky(float v) {
  return v >= 0.f ? v : NEG_SLOPE * v;
}

// ---------------------------------------------------------------------------
// deg + rank capture: rank[e] = edge's arrival index among its dst's edges.
// ---------------------------------------------------------------------------
__global__ __launch_bounds__(256) void deg_kernel(
    const int* __restrict__ ei, int* __restrict__ count,
    int* __restrict__ rank) {
  int e = blockIdx.x * 256 + threadIdx.x;
  if (e >= E_TOT) return;
  int dst = (e < E0_EDGES) ? ei[E0_EDGES + e] : (e - E0_EDGES);
  rank[e] = atomicAdd(&count[dst], 1);
}

// ---------------------------------------------------------------------------
// One-dispatch offset assignment: wave-prescan of cnt + one atomicAdd per
// wave on a global cursor. Offsets are disjoint ranges (not monotonic by
// node id — aggregators use end = off[node] + cnt[node]).
// ---------------------------------------------------------------------------
__global__ __launch_bounds__(256) void reserve_kernel(
    const int* __restrict__ cnt, int* __restrict__ off,
    int* __restrict__ total, int n) {
  const int t = threadIdx.x, lane = t & 63;
  int i = blockIdx.x * 256 + t;
  int v = (i < n) ? cnt[i] : 0;
  int sv = v;
#pragma unroll
  for (int d = 1; d < 64; d <<= 1) {
    int u = __shfl_up(sv, d);
    if (lane >= d) sv += u;
  }
  int base = 0;
  if (lane == 63) base = atomicAdd(total, sv);
  base = __shfl(base, 63);
  if (i < n) off[i] = base + sv - v;   // exclusive within wave + global base
}

// ---------------------------------------------------------------------------
// FUSED: gemm1 (+alphas1) on blocks [0, GEMM1_BLOCKS) and atomic-free scatter
// on the rest. Independent work overlapped in one dispatch.
// gemm1: h1 = x(fp32) @ W1(fp32) -> bf16; fp32 acc; fused per-row alphas.
// Frag maps (mfma_f32_16x16x32_bf16, HW-verified r7):
//   A: row=lane&15, k=8*(lane>>4)+j   B: col=lane&15, same k
//   D: col=lane&15, row=4*(lane>>4)+reg
// ---------------------------------------------------------------------------
__global__ __launch_bounds__(256) void gemm1_scatter_kernel(
    const float* __restrict__ A, const float* __restrict__ B,
    unsigned short* __restrict__ C, float* __restrict__ as1,
    float* __restrict__ ad1, const float* __restrict__ a_s,
    const float* __restrict__ a_d, int M,
    const int* __restrict__ ei, const int* __restrict__ offset,
    const int* __restrict__ rank, int* __restrict__ csr_src) {
  constexpr int K = FIN, BN = 128, KP = K + 8, NF = BN / 16;
  __shared__ unsigned short BT[BN * KP];   // 34.8 KB (unused by scatter blocks)
  const int bid = blockIdx.x;

  if (bid >= GEMM1_BLOCKS) {
    // ---- scatter: no atomics (rank precomputed in deg) ----
    int e = (bid - GEMM1_BLOCKS) * 256 + threadIdx.x;
    if (e >= E_TOT) return;
    int src, dst;
    if (e < E0_EDGES) { src = ei[e]; dst = ei[E0_EDGES + e]; }
    else              { src = e - E0_EDGES; dst = src; }
    csr_src[offset[dst] + rank[e]] = src;
    return;
  }

  // ---- gemm1 ----
  const int bx = bid % NBX1;
  const int gy = bid / NBX1;
  const int tid = threadIdx.x, lane = tid & 63, wid = tid >> 6;
  const int n0 = gy * BN;

  for (int idx = tid; idx < K * (BN / 8); idx += 256) {
    int k = idx >> 4;          // BN/8 == 16
    int c = idx & 15;
    const float* src = &B[(size_t)k * F1 + n0 + c * 8];
    float4 lo = *reinterpret_cast<const float4*>(src);
    float4 hi = *reinterpret_cast<const float4*>(src + 4);
    int nb = c * 8;
    BT[(nb + 0) * KP + k] = f2bf(lo.x); BT[(nb + 1) * KP + k] = f2bf(lo.y);
    BT[(nb + 2) * KP + k] = f2bf(lo.z); BT[(nb + 3) * KP + k] = f2bf(lo.w);
    BT[(nb + 4) * KP + k] = f2bf(hi.x); BT[(nb + 5) * KP + k] = f2bf(hi.y);
    BT[(nb + 6) * KP + k] = f2bf(hi.z); BT[(nb + 7) * KP + k] = f2bf(hi.w);
  }
  __syncthreads();

  const int r0 = (bx * 4 + wid) * 16;
  if (r0 >= M) return;
  const int nlane = lane & 15;
  const int kg    = (lane >> 4) * 8;
  const int arow  = min(r0 + nlane, M - 1);

  f32x4 acc[NF];
#pragma unroll
  for (int nf = 0; nf < NF; ++nf) acc[nf] = (f32x4){0.f, 0.f, 0.f, 0.f};

  const float* ap = &A[(size_t)arow * K + kg];
#pragma unroll
  for (int kk = 0; kk < K; kk += 32) {
    float4 v0 = *reinterpret_cast<const float4*>(ap + kk);
    float4 v1 = *reinterpret_cast<const float4*>(ap + kk + 4);
    bf16x8 a;
    a[0] = (short)f2bf(v0.x); a[1] = (short)f2bf(v0.y);
    a[2] = (short)f2bf(v0.z); a[3] = (short)f2bf(v0.w);
    a[4] = (short)f2bf(v1.x); a[5] = (short)f2bf(v1.y);
    a[6] = (short)f2bf(v1.z); a[7] = (short)f2bf(v1.w);
#pragma unroll
    for (int nf = 0; nf < NF; ++nf) {
      bf16x8 b = *reinterpret_cast<const bf16x8*>(&BT[(nf * 16 + nlane) * KP + kk + kg]);
      acc[nf] = __builtin_amdgcn_mfma_f32_16x16x32_bf16(a, b, acc[nf], 0, 0, 0);
    }
  }

  const int crow = r0 + (lane >> 4) * 4;
#pragma unroll
  for (int nf = 0; nf < NF; ++nf) {
    const int cc = n0 + nf * 16 + nlane;
#pragma unroll
    for (int j = 0; j < 4; ++j) {
      int rr = crow + j;
      if (rr < M) C[(size_t)rr * F1 + cc] = f2bf(acc[nf][j]);
    }
  }

  // fused alphas1: per row, dot over this block's 128 cols (2 heads)
#pragma unroll
  for (int j = 0; j < 4; ++j) {
    float ps0 = 0.f, ps1 = 0.f, pd0 = 0.f, pd1 = 0.f;
#pragma unroll
    for (int nf = 0; nf < NF; ++nf) {
      int col = n0 + nf * 16 + nlane;
      float v = acc[nf][j];
      float sc = a_s[col], dc = a_d[col];
      if (nf < 4) { ps0 = fmaf(v, sc, ps0); pd0 = fmaf(v, dc, pd0); }
      else        { ps1 = fmaf(v, sc, ps1); pd1 = fmaf(v, dc, pd1); }
    }
#pragma unroll
    for (int d = 1; d < 16; d <<= 1) {
      ps0 += __shfl_xor(ps0, d); ps1 += __shfl_xor(ps1, d);
      pd0 += __shfl_xor(pd0, d); pd1 += __shfl_xor(pd1, d);
    }
    int row = crow + j;
    if (nlane == 0 && row < M) {
      float2 s2 = {ps0, ps1}, d2 = {pd0, pd1};
      *reinterpret_cast<float2*>(&as1[row * 4 + gy * 2]) = s2;
      *reinterpret_cast<float2*>(&ad1[row * 4 + gy * 2]) = d2;
    }
  }
}

// ---------------------------------------------------------------------------
// Layer-2 GEMM + fused alphas2. h2 = out1(bf16) @ W2(fp32). BN=64.
// ---------------------------------------------------------------------------
__global__ __launch_bounds__(256) void gemm2_kernel(
    const unsigned short* __restrict__ A, const float* __restrict__ B,
    unsigned short* __restrict__ C, float* __restrict__ as2,
    float* __restrict__ ad2, const float* __restrict__ a_s,
    const float* __restrict__ a_d, int M) {
  constexpr int K = F1, BN = 64, KP = K + 8, NF = BN / 16;
  __shared__ unsigned short BT[BN * KP];   // 33.8 KB
  const int tid = threadIdx.x, lane = tid & 63, wid = tid >> 6;

  for (int idx = tid; idx < K * (BN / 8); idx += 256) {
    int k = idx >> 3;          // BN/8 == 8
    int c = idx & 7;
    const float* src = &B[(size_t)k * C2 + c * 8];
    float4 lo = *reinterpret_cast<const float4*>(src);
    float4 hi = *reinterpret_cast<const float4*>(src + 4);
    int nb = c * 8;
    BT[(nb + 0) * KP + k] = f2bf(lo.x); BT[(nb + 1) * KP + k] = f2bf(lo.y);
    BT[(nb + 2) * KP + k] = f2bf(lo.z); BT[(nb + 3) * KP + k] = f2bf(lo.w);
    BT[(nb + 4) * KP + k] = f2bf(hi.x); BT[(nb + 5) * KP + k] = f2bf(hi.y);
    BT[(nb + 6) * KP + k] = f2bf(hi.z); BT[(nb + 7) * KP + k] = f2bf(hi.w);
  }
  __syncthreads();

  const int r0 = (blockIdx.x * 4 + wid) * 16;
  if (r0 >= M) return;
  const int nlane = lane & 15;
  const int kg    = (lane >> 4) * 8;
  const int arow  = min(r0 + nlane, M - 1);

  f32x4 acc[NF];
#pragma unroll
  for (int nf = 0; nf < NF; ++nf) acc[nf] = (f32x4){0.f, 0.f, 0.f, 0.f};

  const unsigned short* ap = &A[(size_t)arow * K + kg];
#pragma unroll
  for (int kk = 0; kk < K; kk += 32) {
    bf16x8 a = *reinterpret_cast<const bf16x8*>(ap + kk);
#pragma unroll
    for (int nf = 0; nf < NF; ++nf) {
      bf16x8 b = *reinterpret_cast<const bf16x8*>(&BT[(nf * 16 + nlane) * KP + kk + kg]);
      acc[nf] = __builtin_amdgcn_mfma_f32_16x16x32_bf16(a, b, acc[nf], 0, 0, 0);
    }
  }

  const int crow = r0 + (lane >> 4) * 4;
#pragma unroll
  for (int nf = 0; nf < NF; ++nf) {
    const int cc = nf * 16 + nlane;
#pragma unroll
    for (int j = 0; j < 4; ++j) {
      int rr = crow + j;
      if (rr < M) C[(size_t)rr * C2 + cc] = f2bf(acc[nf][j]);
    }
  }

  // fused alphas2 (H=1): dot over all 64 cols
#pragma unroll
  for (int j = 0; j < 4; ++j) {
    float ps = 0.f, pd = 0.f;
#pragma unroll
    for (int nf = 0; nf < NF; ++nf) {
      int col = nf * 16 + nlane;
      float v = acc[nf][j];
      ps = fmaf(v, a_s[col], ps);
      pd = fmaf(v, a_d[col], pd);
    }
#pragma unroll
    for (int d = 1; d < 16; d <<= 1) {
      ps += __shfl_xor(ps, d);
      pd += __shfl_xor(pd, d);
    }
    int row = crow + j;
    if (nlane == 0 && row < M) { as2[row] = ps; ad2[row] = pd; }
  }
}

// ---------------------------------------------------------------------------
// Aggregation layer 1 (round-10 form, measured 67 µs): wave per dst node
// (4/block), single pass, INLINE exp weights, bf16 gathers batched x8.
// end = beg + cnt[node] (offsets are permuted ranges).
// Epilogue: /den, +b1, ReLU -> bf16.
// ---------------------------------------------------------------------------
__global__ __launch_bounds__(256) void aggregate1_kernel(
    const unsigned short* __restrict__ h1b, const float* __restrict__ as,
    const float* __restrict__ ad, const int* __restrict__ csr_src,
    const int* __restrict__ offset, const int* __restrict__ cnt,
    const float* __restrict__ b1, unsigned short* __restrict__ out1b, int n) {
  const int lane = threadIdx.x & 63;
  const int node = blockIdx.x * 4 + (threadIdx.x >> 6);
  if (node >= n) return;
  const int beg = offset[node], end = beg + cnt[node];
  const int hl = lane >> 4;
  const float adh = ad[node * H1 + hl];
  const unsigned loff = (unsigned)(lane * 4);

  float4 acc = make_float4(0.f, 0.f, 0.f, 0.f);
  float den = 0.f;
  int e = beg;
  for (; e + 7 < end; e += 8) {
    int s[8];
    ushort4 r[8];
    float a[8];
#pragma unroll
    for (int i = 0; i < 8; ++i) s[i] = csr_src[e + i];
#pragma unroll
    for (int i = 0; i < 8; ++i)
      r[i] = *reinterpret_cast<const ushort4*>(h1b + (unsigned)(s[i] * F1) + loff);
#pragma unroll
    for (int i = 0; i < 8; ++i) a[i] = as[s[i] * H1 + hl];
#pragma unroll
    for (int i = 0; i < 8; ++i) {
      const float w = __expf(leaky(a[i] + adh));
      den += w;
      acc.x = fmaf(w, bf2f(r[i].x), acc.x);
      acc.y = fmaf(w, bf2f(r[i].y), acc.y);
      acc.z = fmaf(w, bf2f(r[i].z), acc.z);
      acc.w = fmaf(w, bf2f(r[i].w), acc.w);
    }
  }
  for (; e < end; ++e) {
    const int s0 = csr_src[e];
    const float w = __expf(leaky(as[s0 * H1 + hl] + adh));
    den += w;
    const ushort4 r0 = *reinterpret_cast<const ushort4*>(h1b + (unsigned)(s0 * F1) + loff);
    acc.x = fmaf(w, bf2f(r0.x), acc.x);
    acc.y = fmaf(w, bf2f(r0.y), acc.y);
    acc.z = fmaf(w, bf2f(r0.z), acc.z);
    acc.w = fmaf(w, bf2f(r0.w), acc.w);
  }
  const float inv = 1.f / (den + 1e-16f);
  const float4 bb = *reinterpret_cast<const float4*>(&b1[lane * 4]);
  ushort4 ob;
  ob.x = f2bf(fmaxf(fmaf(acc.x, inv, bb.x), 0.f));
  ob.y = f2bf(fmaxf(fmaf(acc.y, inv, bb.y), 0.f));
  ob.z = f2bf(fmaxf(fmaf(acc.z, inv, bb.z), 0.f));
  ob.w = f2bf(fmaxf(fmaf(acc.w, inv, bb.w), 0.f));
  *reinterpret_cast<ushort4*>(&out1b[(size_t)node * F1 + lane * 4]) = ob;
}

// ---------------------------------------------------------------------------
// Aggregation layer 2: wave per dst node, lane owns channel `lane`.
// Single pass, inline exp. end = beg + cnt[node]. Output fp32 (+b2).
// ---------------------------------------------------------------------------
__global__ __launch_bounds__(256) void aggregate2_kernel(
    const unsigned short* __restrict__ h2b, const float* __restrict__ as,
    const float* __restrict__ ad, const int* __restrict__ csr_src,
    const int* __restrict__ offset, const int* __restrict__ cnt,
    const float* __restrict__ b2, float* __restrict__ out, int n) {
  const int lane = threadIdx.x & 63;
  const int node = blockIdx.x * 4 + (threadIdx.x >> 6);
  if (node >= n) return;
  const int beg = offset[node], end = beg + cnt[node];
  const float adv = ad[node];

  float acc = 0.f;
  float den = 0.f;
  int e = beg;
  for (; e + 7 < end; e += 8) {
    int s[8];
    unsigned short r[8];
    float a[8];
#pragma unroll
    for (int i = 0; i < 8; ++i) s[i] = csr_src[e + i];
#pragma unroll
    for (int i = 0; i < 8; ++i) r[i] = h2b[(unsigned)(s[i] * C2) + lane];
#pragma unroll
    for (int i = 0; i < 8; ++i) a[i] = as[s[i]];
#pragma unroll
    for (int i = 0; i < 8; ++i) {
      const float w = __expf(leaky(a[i] + adv));
      den += w;
      acc = fmaf(w, bf2f(r[i]), acc);
    }
  }
  for (; e < end; ++e) {
    const int s0 = csr_src[e];
    const float w = __expf(leaky(as[s0] + adv));
    den += w;
    acc = fmaf(w, bf2f(h2b[(unsigned)(s0 * C2) + lane]), acc);
  }
  out[(size_t)node * C2 + lane] = fmaf(acc, 1.f / (den + 1e-16f), b2[lane]);
}

// ---------------------------------------------------------------------------
extern "C" void kernel_launch(void* const* d_in, const int* in_sizes, int n_in,
                              void* d_out, int out_size, void* d_ws, size_t ws_size,
                              hipStream_t stream) {
  const float* x      = (const float*)d_in[0];
  const int*   ei     = (const int*)d_in[1];      // int32 (JAX x64 disabled)
  const float* W1     = (const float*)d_in[2];
  const float* a_src1 = (const float*)d_in[3];
  const float* a_dst1 = (const float*)d_in[4];
  const float* b1     = (const float*)d_in[5];
  const float* W2     = (const float*)d_in[6];
  const float* a_src2 = (const float*)d_in[7];
  const float* a_dst2 = (const float*)d_in[8];
  const float* b2     = (const float*)d_in[9];
  float*       out    = (float*)d_out;

  const int n = N_NODES;
  const int nchunks = (n + 255) / 256;   // 196

  // Workspace carve (~66 MiB). h2b aliases h1b (dead after aggregate1).
  // cnt + total adjacent -> single memset.
  char* w = (char*)d_ws;
  unsigned short* h1b   = (unsigned short*)w; w += (size_t)n * F1 * 2;     // 25.6 MB
  unsigned short* out1b = (unsigned short*)w; w += (size_t)n * F1 * 2;     // 25.6 MB
  float*          as1   = (float*)w;          w += (size_t)n * H1 * 4;
  float*          ad1   = (float*)w;          w += (size_t)n * H1 * 4;
  float*          as2   = (float*)w;          w += 200192;
  float*          ad2   = (float*)w;          w += 200192;
  int*            cnt   = (int*)w;            w += 200192;
  int*            total = (int*)w;            w += 1024;
  int*            off   = (int*)w;            w += 200192;
  int*            rank  = (int*)w;            w += 3400192;
  int*            csr   = (int*)w;            w += 3400192;
  unsigned short* h2b   = h1b;                // alias

  // --- CSR: deg (captures ranks) + one-dispatch offset reserve ---
  hipMemsetAsync(cnt, 0, 200192 + 1024, stream);   // zeroes cnt AND total
  deg_kernel<<<SCAT_BLOCKS, 256, 0, stream>>>(ei, cnt, rank);
  reserve_kernel<<<nchunks, 256, 0, stream>>>(cnt, off, total, n);

  // --- Fused: gemm1 (+alphas1) overlapped with atomic-free scatter ---
  gemm1_scatter_kernel<<<GEMM1_BLOCKS + SCAT_BLOCKS, 256, 0, stream>>>(
      x, W1, h1b, as1, ad1, a_src1, a_dst1, n, ei, off, rank, csr);

  // --- Layer 1 aggregation (inline exp — round-10 form) ---
  aggregate1_kernel<<<(n + 3) / 4, 256, 0, stream>>>(
      h1b, as1, ad1, csr, off, cnt, b1, out1b, n);

  // --- Layer 2: GEMM (+alphas2) then aggregation ---
  gemm2_kernel<<<(n + 63) / 64, 256, 0, stream>>>(out1b, W2, h2b, as2, ad2,
                                                  a_src2, a_dst2, n);
  aggregate2_kernel<<<(n + 3) / 4, 256, 0, stream>>>(
      h2b, as2, ad2, csr, off, cnt, b2, out, n);
}